// Round 9
// baseline (275.960 us; speedup 1.0000x reference)
//
#include <hip/hip_runtime.h>

typedef __bf16 bf16_t;
typedef __bf16 bf16x8 __attribute__((ext_vector_type(8)));
typedef __bf16 bf16x4 __attribute__((ext_vector_type(4)));
typedef float  f32x4  __attribute__((ext_vector_type(4)));
typedef int    i32x4  __attribute__((ext_vector_type(4)));

#define B_      16
#define L_      2048
#define D_      128
#define QTB     64               // q rows per block = 4 waves x 16
#define NEGINF  (-1.0e9f)
#define SCALE   0.08838834764831845f   // 1/sqrt(128)

#define MFMA_BF16 __builtin_amdgcn_mfma_f32_16x16x32_bf16

// Drain LDS ops before the barrier WITHOUT draining vmcnt: global loads for
// future chunks (and NT attn stores) stay in flight across the barrier.
#define BARRIER() do { asm volatile("s_waitcnt lgkmcnt(0)" ::: "memory"); \
                       __builtin_amdgcn_s_barrier(); } while (0)

// ---------------------------------------------------------------------------
// Prep kernel: blocks 0..255  : V fp32 [B][L][D] -> bf16 VT [B][D][L]
//              blocks 256..511: K fp32 -> bf16 row-major
// ---------------------------------------------------------------------------
__global__ __launch_bounds__(256) void prep_kernel(
    const float* __restrict__ k, const float* __restrict__ v,
    bf16_t* __restrict__ kb, bf16_t* __restrict__ vt)
{
    __shared__ bf16_t tile[128 * 144];
    const int tid = threadIdx.x;
    const int bid = (int)blockIdx.x;

    if (bid < 256) {
        const int b  = bid >> 4;
        const int l0 = (bid & 15) * 128;
        #pragma unroll
        for (int it = 0; it < 16; ++it) {
            int idx = tid + it * 256;
            int row = idx >> 5;
            int dc4 = idx & 31;
            f32x4 x = __builtin_nontemporal_load(
                (const f32x4*)(v + ((size_t)b * L_ + l0 + row) * (size_t)D_ + dc4 * 4));
            #pragma unroll
            for (int i = 0; i < 4; ++i) tile[(dc4 * 4 + i) * 144 + row] = (bf16_t)x[i];
        }
        __syncthreads();
        #pragma unroll
        for (int it = 0; it < 8; ++it) {
            int idx = tid + it * 256;
            int d   = idx >> 4;
            int lc  = idx & 15;
            bf16x8 vec = *(const bf16x8*)&tile[d * 144 + lc * 8];
            *(bf16x8*)(vt + ((size_t)b * D_ + d) * (size_t)L_ + l0 + lc * 8) = vec;
        }
    } else {
        const int idx0 = (bid - 256) * 256 + tid;
        #pragma unroll
        for (int c = 0; c < 16; ++c) {
            int idx = idx0 + c * 65536;
            f32x4 x = __builtin_nontemporal_load((const f32x4*)(k + (size_t)idx * 4));
            bf16x4 o;
            #pragma unroll
            for (int i = 0; i < 4; ++i) o[i] = (bf16_t)x[i];
            *(bf16x4*)(kb + (size_t)idx * 4) = o;
        }
    }
}

// ---------------------------------------------------------------------------
// Main kernel: 512 blocks (2/CU), 4 waves, 64 q-rows per block.
// r8 pipeline (3-slab, distance-2, lgkm-only barriers) with:
//  - mask packed to 1 bit at staging time into persistent mbits[chunk][row]
//  - V slab XOR-swizzled (conflict-free ds_read_b128)
//  - two independent barrier domains per CU
// ---------------------------------------------------------------------------
template <bool WS>
__global__ __launch_bounds__(256, 1) void sdpa_kernel(
    const float* __restrict__ q, const float* __restrict__ k,
    const float* __restrict__ v, const int* __restrict__ mask,
    const bf16_t* __restrict__ kb, const bf16_t* __restrict__ vt,
    float* __restrict__ out, float* __restrict__ attn)
{
    __shared__ char     Kst[3][8192];     // 24KB  K slabs [32][128] bf16, XOR-swz
    __shared__ char     Vst[3][8192];     // 24KB  V slabs [128 d][32 k] bf16, XOR-swz
    __shared__ unsigned mbits[64 * 64];   // 16KB  packed mask bits [chunk][row]
    __shared__ bf16_t   plds[4][16][40];  //  5KB  P bounce (per-wave)

    const int tid = threadIdx.x;
    const int w   = tid >> 6;             // wave 0..3
    const int l   = tid & 63;
    const int li  = l & 15;
    const int lg  = l >> 4;

    // XCD-chunked bijective swizzle (512 % 8 == 0): 2 whole batches per XCD
    const int bid  = (int)blockIdx.x;
    const int bid2 = (bid & 7) * 64 + (bid >> 3);
    const int b    = bid2 >> 5;           // 32 q-tiles per batch
    const int qt   = bid2 & 31;
    const int qbase = qt * QTB;

    const size_t bq = (size_t)b * L_;

    const float*  qp   = q  + (bq + qbase) * (size_t)D_;
    const bf16_t* kbp  = kb + bq * (size_t)D_;
    const float*  kp   = k  + bq * (size_t)D_;
    const bf16_t* vtp  = vt + (size_t)b * D_ * (size_t)L_;
    const float*  vp   = v  + bq * (size_t)D_;
    float* attnrow = attn + (bq + qbase + (size_t)(w * 16 + li)) * (size_t)L_;
    float* outp    = out  + (bq + qbase) * (size_t)D_;

    // ---------------- Q B-fragments (pre-scaled by 1/temper)
    bf16x8 aq[4];
    #pragma unroll
    for (int ds = 0; ds < 4; ++ds) {
        const float* p = qp + (size_t)(w * 16 + li) * D_ + ds * 32 + lg * 8;
        f32x4 x0 = *(const f32x4*)p;
        f32x4 x1 = *(const f32x4*)(p + 4);
        bf16x8 a;
        #pragma unroll
        for (int u = 0; u < 4; ++u) {
            a[u]     = (bf16_t)(x0[u] * SCALE);
            a[4 + u] = (bf16_t)(x1[u] * SCALE);
        }
        aq[ds] = a;
    }

    // ---------------- cooperative staging geometry (256 threads)
    // K: 32 rows x 256B; thread covers (row tid>>3, 16B slots ks and ks+8)
    const int krow = tid >> 3, ks = tid & 7;
    const int kdst = krow * 256 + ((ks * 16) ^ ((krow & 7) << 4));  // slot+8 at +128
    const bf16_t* ksrcb = kbp + (size_t)krow * D_ + ks * 8;
    const float*  ksrcf = kp  + (size_t)krow * D_ + ks * 8;

    // V: 128 d-rows x 64B; thread covers (d=tid>>1, 16B slots vs*2, vs*2+1)
    const int vrow = tid >> 1, vs = tid & 1;
    const int vswz = (vrow >> 1) & 3;
    const int vdst0 = vrow * 64 + (((vs * 2)     ^ vswz) << 4);
    const int vdst1 = vrow * 64 + (((vs * 2 + 1) ^ vswz) << 4);
    const bf16_t* vsrcb = vtp + (size_t)vrow * L_;

    // mask: thread covers (row tid&63, 8 cols at quarter w)
    const int mr = tid & 63;
    const int* msrc = mask + (size_t)(bq + qbase + mr) * L_ + w * 8;

    auto issueK = [&](int c, i32x4& r0, i32x4& r1, f32x4* rf) {
        if constexpr (WS) {
            r0 = *(const i32x4*)(ksrcb + (size_t)c * 32 * D_);
            r1 = *(const i32x4*)(ksrcb + (size_t)c * 32 * D_ + 64);
        } else {
            rf[0] = *(const f32x4*)(ksrcf + (size_t)c * 32 * D_);
            rf[1] = *(const f32x4*)(ksrcf + (size_t)c * 32 * D_ + 4);
            rf[2] = *(const f32x4*)(ksrcf + (size_t)c * 32 * D_ + 64);
            rf[3] = *(const f32x4*)(ksrcf + (size_t)c * 32 * D_ + 68);
        }
    };
    auto writeK = [&](int sl, const i32x4& r0, const i32x4& r1, const f32x4* rf) {
        char* d = Kst[sl] + kdst;
        if constexpr (WS) {
            *(i32x4*)d = r0;
            *(i32x4*)(d + 128) = r1;
        } else {
            bf16x8 o0, o1;
            #pragma unroll
            for (int u = 0; u < 4; ++u) {
                o0[u] = (bf16_t)rf[0][u]; o0[4+u] = (bf16_t)rf[1][u];
                o1[u] = (bf16_t)rf[2][u]; o1[4+u] = (bf16_t)rf[3][u];
            }
            *(bf16x8*)d = o0;
            *(bf16x8*)(d + 128) = o1;
        }
    };
    auto issueM = [&](int c, i32x4& m0, i32x4& m1) {
        m0 = __builtin_nontemporal_load((const i32x4*)(msrc + c * 32));
        m1 = __builtin_nontemporal_load((const i32x4*)(msrc + c * 32 + 4));
    };
    auto writeM = [&](int c, const i32x4& m0, const i32x4& m1) {
        unsigned by = (m0[0] != 0 ?   1u : 0u) | (m0[1] != 0 ?   2u : 0u)
                    | (m0[2] != 0 ?   4u : 0u) | (m0[3] != 0 ?   8u : 0u)
                    | (m1[0] != 0 ?  16u : 0u) | (m1[1] != 0 ?  32u : 0u)
                    | (m1[2] != 0 ?  64u : 0u) | (m1[3] != 0 ? 128u : 0u);
        ((char*)mbits)[c * 256 + mr * 4 + w] = (char)by;
    };
    auto issueV = [&](int c, i32x4& r0, i32x4& r1, float* vf) {
        if constexpr (WS) {
            r0 = *(const i32x4*)(vsrcb + c * 32 + vs * 16);
            r1 = *(const i32x4*)(vsrcb + c * 32 + vs * 16 + 8);
        } else {
            #pragma unroll
            for (int u = 0; u < 8; ++u) {
                vf[u]     = vp[(size_t)(c * 32 + vs * 16 + u) * D_ + vrow];
                vf[8 + u] = vp[(size_t)(c * 32 + vs * 16 + 8 + u) * D_ + vrow];
            }
        }
    };
    auto writeV = [&](int sl, const i32x4& r0, const i32x4& r1, const float* vf) {
        if constexpr (WS) {
            *(i32x4*)(Vst[sl] + vdst0) = r0;
            *(i32x4*)(Vst[sl] + vdst1) = r1;
        } else {
            bf16x8 o0, o1;
            #pragma unroll
            for (int u = 0; u < 8; ++u) { o0[u] = (bf16_t)vf[u]; o1[u] = (bf16_t)vf[8+u]; }
            *(bf16x8*)(Vst[sl] + vdst0) = o0;
            *(bf16x8*)(Vst[sl] + vdst1) = o1;
        }
    };

    const int xr = (li & 7) << 4;   // K read-side XOR

    // QK^T for a chunk from LDS slot -> a0 (k rows +0..15), a1 (+16..31)
    auto qkt = [&](int sl, f32x4& a0, f32x4& a1) {
        const char* Ks = Kst[sl];
        f32x4 r0 = {0.f,0.f,0.f,0.f}, r1 = {0.f,0.f,0.f,0.f};
        #pragma unroll
        for (int ds = 0; ds < 4; ++ds) {
            bf16x8 k0 = *(const bf16x8*)(Ks + li * 256 + ((ds * 64 + lg * 16) ^ xr));
            r0 = MFMA_BF16(k0, aq[ds], r0, 0, 0, 0);
        }
        #pragma unroll
        for (int ds = 0; ds < 4; ++ds) {
            bf16x8 k1 = *(const bf16x8*)(Ks + (16 + li) * 256 + ((ds * 64 + lg * 16) ^ xr));
            r1 = MFMA_BF16(k1, aq[ds], r1, 0, 0, 0);
        }
        a0 = r0; a1 = r1;
    };
    // this lane's 8 mask bits for chunk c (rows lg*4+r and 16+lg*4+r)
    auto maskbyte = [&](int c) -> unsigned {
        unsigned word = mbits[c * 64 + w * 16 + li];
        return ((word >> (lg * 4)) & 0xFu) | (((word >> (16 + lg * 4)) & 0xFu) << 4);
    };

    // ================= PASS 1: online masked max/sum ========================
    float m_run = -3.4e38f, l_run = 0.f;
    {
        auto p1c = [&](int c, int sl) {
            f32x4 a0, a1;
            qkt(sl, a0, a1);
            const unsigned byte = maskbyte(c);
            float s0[4], s1[4];
            #pragma unroll
            for (int r = 0; r < 4; ++r) {
                s0[r] = a0[r] + (((byte >> r)       & 1u) ? 0.f : NEGINF);
                s1[r] = a1[r] + (((byte >> (4 + r)) & 1u) ? 0.f : NEGINF);
            }
            float mx = fmaxf(fmaxf(fmaxf(s0[0], s0[1]), fmaxf(s0[2], s0[3])),
                             fmaxf(fmaxf(s1[0], s1[1]), fmaxf(s1[2], s1[3])));
            mx = fmaxf(mx, m_run);
            float acc = 0.f;
            #pragma unroll
            for (int r = 0; r < 4; ++r)
                acc += __expf(s0[r] - mx) + __expf(s1[r] - mx);
            l_run = l_run * __expf(m_run - mx) + acc;
            m_run = mx;
        };

        i32x4 kA0{}, kA1{}, kB0{}, kB1{}, mA0{}, mA1{}, mB0{}, mB1{};
        f32x4 kfA[4], kfB[4];
        issueK(0, kA0, kA1, kfA); issueM(0, mA0, mA1);
        issueK(1, kB0, kB1, kfB); issueM(1, mB0, mB1);
        writeK(0, kA0, kA1, kfA); writeM(0, mA0, mA1);
        BARRIER();
        int s0i = 0, s1i = 1, s2i = 2;
        #pragma unroll 1
        for (int c = 0; c < 64; c += 2) {
            if (c + 2 < 64) { issueK(c + 2, kA0, kA1, kfA); issueM(c + 2, mA0, mA1); }
            writeK(s1i, kB0, kB1, kfB); writeM(c + 1, mB0, mB1);
            BARRIER();
            p1c(c, s0i);
            { int t = s0i; s0i = s1i; s1i = s2i; s2i = t; }
            if (c + 3 < 64) { issueK(c + 3, kB0, kB1, kfB); issueM(c + 3, mB0, mB1); }
            if (c + 2 < 64) { writeK(s1i, kA0, kA1, kfA); writeM(c + 2, mA0, mA1); }
            BARRIER();
            p1c(c + 1, s0i);
            { int t = s0i; s0i = s1i; s1i = s2i; s2i = t; }
        }
    }

    // merge m/sum across the 4 lane-groups (lanes li, li+16, li+32, li+48)
    #pragma unroll
    for (int off = 16; off < 64; off <<= 1) {
        float mo = __shfl_xor(m_run, off);
        float lo = __shfl_xor(l_run, off);
        float mn = fmaxf(m_run, mo);
        l_run = l_run * __expf(m_run - mn) + lo * __expf(mo - mn);
        m_run = mn;
    }
    const float inv_l = 1.f / l_run;

    // ================= PASS 2: recompute + attn write + PV ==================
    f32x4 pv[8];
    #pragma unroll
    for (int dt = 0; dt < 8; ++dt) pv[dt] = {0.f, 0.f, 0.f, 0.f};

    {
        auto p2c = [&](int c, int sl) {
            f32x4 a0, a1;
            qkt(sl, a0, a1);
            const unsigned byte = maskbyte(c);
            f32x4 o0, o1; bf16x4 pb0, pb1;
            #pragma unroll
            for (int r = 0; r < 4; ++r) {
                float sa = a0[r] + (((byte >> r)       & 1u) ? 0.f : NEGINF);
                float sb = a1[r] + (((byte >> (4 + r)) & 1u) ? 0.f : NEGINF);
                float p0 = __expf(sa - m_run);
                float p1 = __expf(sb - m_run);
                o0[r] = p0 * inv_l;  o1[r] = p1 * inv_l;
                pb0[r] = (bf16_t)p0; pb1[r] = (bf16_t)p1;
            }
            // attn: 4-lane lg group covers a full 128B line per q-row per chunk
            __builtin_nontemporal_store(o0, (f32x4*)(attnrow + c * 32 + lg * 4));
            __builtin_nontemporal_store(o1, (f32x4*)(attnrow + c * 32 + 16 + lg * 4));
            // C-layout -> A-frag via per-wave LDS bounce
            *(bf16x4*)&plds[w][li][lg * 4]      = pb0;
            *(bf16x4*)&plds[w][li][16 + lg * 4] = pb1;
            bf16x8 pa = *(const bf16x8*)&plds[w][li][lg * 8];
            const char* Vs = Vst[sl];
            #pragma unroll
            for (int dt = 0; dt < 8; ++dt) {
                const int vr = dt * 16 + li;
                bf16x8 vbf = *(const bf16x8*)(Vs + vr * 64 + (((lg ^ ((li >> 1) & 3))) << 4));
                pv[dt] = MFMA_BF16(pa, vbf, pv[dt], 0, 0, 0);
            }
        };

        BARRIER();   // all pass-1 slab reads complete before restaging
        i32x4 kA0{}, kA1{}, kB0{}, kB1{}, vA0{}, vA1{}, vB0{}, vB1{};
        f32x4 kfA[4], kfB[4];
        float vfA[16], vfB[16];
        issueK(0, kA0, kA1, kfA); issueV(0, vA0, vA1, vfA);
        issueK(1, kB0, kB1, kfB); issueV(1, vB0, vB1, vfB);
        writeK(0, kA0, kA1, kfA); writeV(0, vA0, vA1, vfA);
        BARRIER();
        int s0i = 0, s1i = 1, s2i = 2;
        #pragma unroll 1
        for (int c = 0; c < 64; c += 2) {
            if (c + 2 < 64) { issueK(c + 2, kA0, kA1, kfA); issueV(c + 2, vA0, vA1, vfA); }
            writeK(s1i, kB0, kB1, kfB); writeV(s1i, vB0, vB1, vfB);
            BARRIER();
            p2c(c, s0i);
            { int t = s0i; s0i = s1i; s1i = s2i; s2i = t; }
            if (c + 3 < 64) { issueK(c + 3, kB0, kB1, kfB); issueV(c + 3, vB0, vB1, vfB); }
            if (c + 2 < 64) { writeK(s1i, kA0, kA1, kfA); writeV(s1i, vA0, vA1, vfA); }
            BARRIER();
            p2c(c + 1, s0i);
            { int t = s0i; s0i = s1i; s1i = s2i; s2i = t; }
        }
    }

    // ---------------- Epilogue: out[q][d] = pv * inv_l[q]
    #pragma unroll
    for (int r = 0; r < 4; ++r) {
        const float il = __shfl(inv_l, lg * 4 + r);
        float* orow = outp + (size_t)(w * 16 + lg * 4 + r) * D_ + li;
        #pragma unroll
        for (int dt = 0; dt < 8; ++dt)
            __builtin_nontemporal_store(pv[dt][r] * il, orow + dt * 16);
    }
}

extern "C" void kernel_launch(void* const* d_in, const int* in_sizes, int n_in,
                              void* d_out, int out_size, void* d_ws, size_t ws_size,
                              hipStream_t stream) {
    const float* q    = (const float*)d_in[0];
    const float* k    = (const float*)d_in[1];
    const float* v    = (const float*)d_in[2];
    const int*   mask = (const int*)d_in[3];

    float* out  = (float*)d_out;
    float* attn = out + (size_t)B_ * L_ * D_;

    const size_t VT_BYTES = (size_t)B_ * D_ * L_ * 2;   // 8 MB
    const size_t KB_BYTES = (size_t)B_ * L_ * D_ * 2;   // 8 MB
    const bool ws_ok = ws_size >= VT_BYTES + KB_BYTES;
    bf16_t* vt = (bf16_t*)d_ws;
    bf16_t* kb = (bf16_t*)((char*)d_ws + VT_BYTES);

    if (ws_ok) {
        hipLaunchKernelGGL(prep_kernel, dim3(512), dim3(256), 0, stream, k, v, kb, vt);
        hipLaunchKernelGGL(sdpa_kernel<true>, dim3(512), dim3(256), 0, stream,
                           q, k, v, mask, kb, vt, out, attn);
    } else {
        hipLaunchKernelGGL(sdpa_kernel<false>, dim3(512), dim3(256), 0, stream,
                           q, k, v, mask, kb, vt, out, attn);
    }
}